// Round 4
// baseline (5836.398 us; speedup 1.0000x reference)
//
#include <hip/hip_runtime.h>
#include <hip/hip_bf16.h>
#include <cstdint>
#include <cstddef>

// LSTM encoder: B=64, T=512, D=256, UNITS=1024, gates G=4096 (i|f|g|o).
// Persistent, 256 WGs x 128 threads. WG = (unit-group g8 = wg>>1: 8 units) x
// (row-half = wg&1: 32 batch rows).
// R4: BARRIER-FREE epoch-tagged exchange. h is exchanged as 8B atomic chunks
// {2xbf16 | u32 tag = step+1}. Producers store fire-and-forget (no ack wait, no
// flags, no counters). Consumers pipeline 64 bypass loads (staged vmcnt ladder),
// MFMA optimistically, OR-accumulate tag^expected; any stale chunk -> redo pass
// (acc re-init from saved x@W). 2-buffer parity is race-free: overwrite of buf b
// requires consuming h(t), which requires all stores of h(t), which requires all
// reads of buf b done. Waves of a WG are fully independent (disjoint rows,
// intra-wave zlds transpose) -> no in-loop __syncthreads at all.

#define NWG    256
#define KSTEPS 40
#define SEQ_N  33554432    // 64*512*1024

typedef __attribute__((ext_vector_type(8))) short short8;
typedef __attribute__((ext_vector_type(4))) float floatx4;
typedef __attribute__((ext_vector_type(2))) float floatx2;
typedef __attribute__((ext_vector_type(4))) int   intx4;

union fragu { int i[4]; short8 s; };

static __device__ __forceinline__ short f2bf(float f) {
  __hip_bfloat16 h = __float2bfloat16(f);
  return *reinterpret_cast<short*>(&h);
}
static __device__ __forceinline__ float sigm(float x) { return 1.f / (1.f + __expf(-x)); }
static __device__ __forceinline__ float tanh_fast(float x) {
  float xc = fminf(fmaxf(x, -15.f), 15.f);
  float e  = __expf(2.f * xc);
  return (e - 1.f) / (e + 1.f);
}

// ---- prep: pack [U;W] into per-unit-group MFMA B-fragment order, bf16 ----
__global__ void pack_weights(const float* __restrict__ W, const float* __restrict__ U,
                             short* __restrict__ upack) {
  int idx  = blockIdx.x * 256 + threadIdx.x;   // 0 .. 655359
  int lane = idx & 63;
  int kk   = (idx >> 6) % KSTEPS;
  int ct   = ((idx >> 6) / KSTEPS) & 1;
  int g8   = idx / (KSTEPS * 64 * 2);
  int quad = lane >> 4, n = lane & 15;
  int col  = (n >> 2) * 1024 + g8 * 8 + ct * 4 + (n & 3);
  int k0   = kk * 32 + quad * 8;
  short8 v;
#pragma unroll
  for (int j = 0; j < 8; ++j) {
    int k = k0 + j;
    float f = (k < 1024) ? U[(size_t)k * 4096 + col] : W[(size_t)(k - 1024) * 4096 + col];
    v[j] = f2bf(f);
  }
  *reinterpret_cast<short8*>(upack + (size_t)idx * 8) = v;
}

__global__ void convert_x(const float* __restrict__ x, short* __restrict__ xbf) {
  int idx = blockIdx.x * 256 + threadIdx.x;
  const float* xp = x + (size_t)idx * 8;
  short8 v;
#pragma unroll
  for (int j = 0; j < 8; ++j) v[j] = f2bf(xp[j]);
  *reinterpret_cast<short8*>(xbf + (size_t)idx * 8) = v;
}

// h(0)=0 with tag 1 in buf0; buf1 tag 0 ("never written"). At the coherence point.
__global__ void init_state(unsigned long long* __restrict__ hbuf) {
  int idx = blockIdx.x * 256 + threadIdx.x;    // 256 blocks -> 65536
  unsigned long long v = (idx < 32768) ? (1ull << 32) : 0ull;
  __hip_atomic_store(&hbuf[idx], v, __ATOMIC_RELAXED, __HIP_MEMORY_SCOPE_AGENT);
}

// two 16B bypass loads (= 4 tagged 8B chunks) for K-step J. "memory" clobber
// pins program order of surrounding stores so the vmcnt ladder stays exact.
#define HIS(J, O0, O1)                                                      \
  asm volatile("global_load_dwordx4 %0, %2, off offset:" #O0 " sc0 sc1\n\t" \
               "global_load_dwordx4 %1, %2, off offset:" #O1 " sc0 sc1"     \
               : "=v"(La[(J)&7]), "=v"(Lb[(J)&7]) : "v"(hb) : "memory");

#define WAITVM(N)                                        \
  asm volatile("s_waitcnt vmcnt(" #N ")" ::: "memory");  \
  __builtin_amdgcn_sched_barrier(0);

#define BMFMA __builtin_amdgcn_mfma_f32_16x16x32_bf16

// consume K-step J: tag-check + 2 MFMAs (tile0 from VGPR weights, tile1 from LDS)
#define HCONS(J, W)                                                          \
  WAITVM(W)                                                                  \
  { intx4 A = La[(J)&7], B = Lb[(J)&7];                                      \
    ok |= (A[1] ^ T) | (A[3] ^ T) | (B[1] ^ T) | (B[3] ^ T);                 \
    fragu uf; uf.i[0] = A[0]; uf.i[1] = A[2]; uf.i[2] = B[0]; uf.i[3] = B[2];\
    short8 bb = *reinterpret_cast<const short8*>(wlds + (((J)*64) + lane)*8);\
    if ((J) & 1) { t01 = BMFMA(uf.s, wU0[J], t01, 0,0,0);                    \
                   t11 = BMFMA(uf.s, bb,     t11, 0,0,0); }                  \
    else         { t00 = BMFMA(uf.s, wU0[J], t00, 0,0,0);                    \
                   t10 = BMFMA(uf.s, bb,     t10, 0,0,0); } }

// ---- persistent stepper ----
__global__ __launch_bounds__(128, 1) void lstm_persist(
    const short* __restrict__ xbf,            // [64][512][256] bf16
    const short* __restrict__ upack,          // packed B frags, 40960 shorts/group
    const float* __restrict__ bias,           // [4096] f32
    unsigned long long* __restrict__ hbuf64,  // [2][64][512] {2xbf16|tag} chunks
    float* __restrict__ out)
{
  __shared__ short wlds[20480];       // tile1 weights, 40KB
  __shared__ float zlds[32 * 36];     // gate staging (intra-wave transpose)

  const int wg   = blockIdx.x;
  const int g8   = wg >> 1;                  // unit group (8 units)
  const int half = wg & 1;                   // batch-row half (32 rows)
  const int tid  = threadIdx.x;              // 0..127
  const int wave = tid >> 6;                 // 0..1
  const int lane = tid & 63;
  const int quad = lane >> 4;
  const int l15  = lane & 15;
  const int arow = half * 32 + wave * 16 + l15;   // global batch row (A operand)
  const int eb   = tid >> 2;                 // local row 0..31 (elementwise)
  const int gr   = half * 32 + eb;           // global row
  const int q    = tid & 3;                  // owns units u0, u0+1 (one 8B chunk)
  const int u0   = g8 * 8 + q * 2;
  const float bi0 = bias[u0],        bi1 = bias[u0 + 1];
  const float bf0 = bias[1024 + u0], bf1 = bias[1025 + u0];
  const float bg0 = bias[2048 + u0], bg1 = bias[2049 + u0];
  const float bo0 = bias[3072 + u0], bo1 = bias[3073 + u0];
  float c0 = 0.f, c1 = 0.f;

  // ---- tile0 weights resident in VGPRs; tile1 staged to LDS ----
  const short* wsrc = upack + (size_t)g8 * 40960;
  short8 wU0[32];   // tile0 h@U, ksteps 0..31
  short8 wX0[8];    // tile0 x@W, ksteps 32..39
#pragma unroll
  for (int s = 0; s < 32; ++s)
    wU0[s] = *reinterpret_cast<const short8*>(wsrc + (s * 64 + lane) * 8);
#pragma unroll
  for (int s = 0; s < 8; ++s)
    wX0[s] = *reinterpret_cast<const short8*>(wsrc + ((32 + s) * 64 + lane) * 8);
  {
    const short* src1 = wsrc + 20480;
#pragma unroll
    for (int i = 0; i < 20; ++i) {
      int id = i * 128 + tid;
      *reinterpret_cast<short8*>(wlds + id * 8) =
          *reinterpret_cast<const short8*>(src1 + id * 8);
    }
  }
  __syncthreads();

  const short* xrow = xbf + (size_t)arow * 512 * 256 + quad * 8;

  short8 xv[8];                              // prefetched x A-frags
  auto load_x = [&](int t) {
    const short* xp = xrow + t * 256;
#pragma unroll
    for (int it = 0; it < 4; ++it) {
      xv[2*it]   = *reinterpret_cast<const short8*>(xp);
      xv[2*it+1] = *reinterpret_cast<const short8*>(xp + 32);
      xp += 64;
    }
  };
  auto mfma_x = [&](floatx4& x00, floatx4& x01, floatx4& x10, floatx4& x11) {
    floatx4 a0 = {0.f,0.f,0.f,0.f}, a1 = a0, a2 = a0, a3 = a0;
#pragma unroll
    for (int it = 0; it < 4; ++it) {
      short8 b10 = *reinterpret_cast<const short8*>(wlds + ((32 + 2*it) * 64 + lane) * 8);
      short8 b11 = *reinterpret_cast<const short8*>(wlds + ((33 + 2*it) * 64 + lane) * 8);
      a0 = BMFMA(xv[2*it],   wX0[2*it],   a0, 0, 0, 0);
      a1 = BMFMA(xv[2*it+1], wX0[2*it+1], a1, 0, 0, 0);
      a2 = BMFMA(xv[2*it],   b10,         a2, 0, 0, 0);
      a3 = BMFMA(xv[2*it+1], b11,         a3, 0, 0, 0);
    }
    x00 = a0; x01 = a1; x10 = a2; x11 = a3;
  };

  floatx4 x00, x01, x10, x11;
  load_x(0);
  mfma_x(x00, x01, x10, x11);
  asm volatile("s_waitcnt vmcnt(0)" ::: "memory");   // clean FIFO before pass 0

  for (int t = 0; t < 512; ++t) {
    // ---- consume h(t): tagged pass loop, redo until all tags == t+1 ----
    const char* hb = (const char*)hbuf64 + ((size_t)(t & 1) << 18)
                   + (size_t)arow * 4096 + quad * 32;
    const int T = t + 1;
    floatx4 a00, a10;
    {
      intx4 La[8], Lb[8];
      for (;;) {
        int ok = 0;
        floatx4 t00 = x00, t01 = x01, t10 = x10, t11 = x11;
        HIS(0,0,16)       HIS(1,128,144)    HIS(2,256,272)    HIS(3,384,400)
        HIS(4,512,528)    HIS(5,640,656)    HIS(6,768,784)    HIS(7,896,912)
        HCONS(0,14)  HIS(8,1024,1040)
        HCONS(1,14)  HIS(9,1152,1168)
        HCONS(2,14)  HIS(10,1280,1296)
        HCONS(3,14)  HIS(11,1408,1424)
        HCONS(4,14)  HIS(12,1536,1552)
        HCONS(5,14)  HIS(13,1664,1680)
        HCONS(6,14)  HIS(14,1792,1808)
        HCONS(7,14)  HIS(15,1920,1936)
        HCONS(8,14)  HIS(16,2048,2064)
        HCONS(9,14)  HIS(17,2176,2192)
        HCONS(10,14) HIS(18,2304,2320)
        HCONS(11,14) HIS(19,2432,2448)
        HCONS(12,14) HIS(20,2560,2576)
        HCONS(13,14) HIS(21,2688,2704)
        HCONS(14,14) HIS(22,2816,2832)
        HCONS(15,14) HIS(23,2944,2960)
        HCONS(16,14) HIS(24,3072,3088)
        HCONS(17,14) HIS(25,3200,3216)
        HCONS(18,14) HIS(26,3328,3344)
        HCONS(19,14) HIS(27,3456,3472)
        HCONS(20,14) HIS(28,3584,3600)
        HCONS(21,14) HIS(29,3712,3728)
        HCONS(22,14) HIS(30,3840,3856)
        HCONS(23,14) HIS(31,3968,3984)
        HCONS(24,14) HCONS(25,12) HCONS(26,10) HCONS(27,8)
        HCONS(28,6)  HCONS(29,4)  HCONS(30,2)  HCONS(31,0)
        if (__all(ok == 0)) { a00 = t00 + t01; a10 = t10 + t11; break; }
      }
    }

    if (t < 511) load_x(t + 1);   // cacheable; overlaps below

    // C layout: col = lane&15 (= gate*4+uit), row = quad*4 + r (local tile row)
#pragma unroll
    for (int r = 0; r < 4; ++r) {
      int zr = (wave * 16 + quad * 4 + r) * 36;
      zlds[zr + l15]      = a00[r];
      zlds[zr + 18 + l15] = a10[r];
    }
    asm volatile("s_waitcnt lgkmcnt(0)" ::: "memory");   // intra-wave transpose

    const float* zb = zlds + eb * 36 + (q >> 1) * 18 + (q & 1) * 2;
    float zi0 = zb[0]  + bi0, zi1 = zb[1]  + bi1;
    float zf0 = zb[4]  + bf0, zf1 = zb[5]  + bf1;
    float zg0 = zb[8]  + bg0, zg1 = zb[9]  + bg1;
    float zo0 = zb[12] + bo0, zo1 = zb[13] + bo1;
    float i0 = sigm(zi0), f0 = sigm(zf0), g0 = tanh_fast(zg0), o0 = sigm(zo0);
    float i1 = sigm(zi1), f1 = sigm(zf1), g1 = tanh_fast(zg1), o1 = sigm(zo1);
    c0 = f0 * c0 + i0 * g0;
    c1 = f1 * c1 + i1 * g1;
    float h0 = o0 * tanh_fast(c0);
    float h1 = o1 * tanh_fast(c1);

    unsigned int data = (unsigned int)(unsigned short)f2bf(h0) |
                        ((unsigned int)(unsigned short)f2bf(h1) << 16);
    floatx2 hv = {h0, h1};

    if (t < 511) {
      // fire-and-forget tagged store of h(t+1): {data | tag t+2}
      unsigned long long v = (unsigned long long)data |
                             ((unsigned long long)(unsigned int)(t + 2) << 32);
      __hip_atomic_store(hbuf64 + ((size_t)((t + 1) & 1) << 15)
                           + (size_t)gr * 512 + g8 * 4 + q,
                         v, __ATOMIC_RELAXED, __HIP_MEMORY_SCOPE_AGENT);
      *reinterpret_cast<floatx2*>(out + ((size_t)gr * 512 + t) * 1024 + u0) = hv;
      mfma_x(x00, x01, x10, x11);   // x@W(t+1) while stores fly
    } else {
      floatx2 cv = {c0, c1};
      *reinterpret_cast<floatx2*>(out + ((size_t)gr * 512 + 511) * 1024 + u0) = hv;
      *reinterpret_cast<floatx2*>(out + (size_t)SEQ_N + (size_t)gr * 1024 + u0) = hv;
      *reinterpret_cast<floatx2*>(out + (size_t)SEQ_N + 65536 + (size_t)gr * 1024 + u0) = cv;
    }
  }
}

extern "C" void kernel_launch(void* const* d_in, const int* in_sizes, int n_in,
                              void* d_out, int out_size, void* d_ws, size_t ws_size,
                              hipStream_t stream) {
  const float* x    = (const float*)d_in[0];
  const float* W    = (const float*)d_in[1];
  const float* U    = (const float*)d_in[2];
  const float* bias = (const float*)d_in[3];
  float* out = (float*)d_out;
  char* ws = (char*)d_ws;

  short* upack = (short*)ws;                      // 10,485,760 B
  short* xbf   = (short*)(ws + 10485760);         // 16,777,216 B
  unsigned long long* hbuf = (unsigned long long*)(ws + 27262976); // 524,288 B
  (void)in_sizes; (void)n_in; (void)out_size; (void)ws_size;

  init_state<<<256, 256, 0, stream>>>(hbuf);
  pack_weights<<<2560, 256, 0, stream>>>(W, U, upack);
  convert_x<<<4096, 256, 0, stream>>>(x, xbf);
  lstm_persist<<<NWG, 128, 0, stream>>>(xbf, upack, bias, hbuf, out);
}

// Round 7
// 2470.441 us; speedup vs baseline: 2.3625x; 2.3625x over previous
//
#include <hip/hip_runtime.h>
#include <hip/hip_bf16.h>
#include <cstdint>
#include <cstddef>

// LSTM encoder: B=64, T=512, D=256, UNITS=1024, gates G=4096 (i|f|g|o).
// R7: 8 LOGICAL machines of 32 WGs (machine = blockIdx>>5), each machine owns
// 8 batch rows; WG owns 32 units x 8 rows. Sync + h-exchange at DEVICE scope
// (MALL) -- placement-independent, uses only R3-proven primitives (relaxed
// AGENT atomics, sc0 sc1 asm loads, monotonic flags). vs R3: barrier group
// 256->32 (8 decoupled machines, smaller skew), per-WG h-read 32KB->16KB staged
// once to LDS and shared by 4 waves, contiguous flags (2 lines/machine),
// 4x MFMA per WG amortizes fixed sync cost. U-weights VGPR-resident; x@W
// B-frags from cached upack; h in granule-even XOR-swizzled LDS. LDS ~37KB.

#define SEQ_N  33554432    // 64*512*1024

typedef __attribute__((ext_vector_type(8))) short short8;
typedef __attribute__((ext_vector_type(4))) float floatx4;

#define BMFMA __builtin_amdgcn_mfma_f32_16x16x32_bf16

static __device__ __forceinline__ short f2bf(float f) {
  __hip_bfloat16 h = __float2bfloat16(f);
  return *reinterpret_cast<short*>(&h);
}
static __device__ __forceinline__ float sigm(float x) { return 1.f / (1.f + __expf(-x)); }
static __device__ __forceinline__ float tanh_fast(float x) {
  float xc = fminf(fmaxf(x, -15.f), 15.f);
  float e  = __expf(2.f * xc);
  return (e - 1.f) / (e + 1.f);
}

// ---- prep: pack [U;W] B-frags per unit-group ug (32 units), col-tile ct (4 units) ----
// upack[ug(32)][ct(8)][kk(40)][lane(64)][8 shorts]
__global__ void pack_weights(const float* __restrict__ W, const float* __restrict__ U,
                             short* __restrict__ upack) {
  int idx  = blockIdx.x * 256 + threadIdx.x;   // 0 .. 655359
  int lane = idx & 63;
  int frag = idx >> 6;
  int kk   = frag % 40;
  int ct   = (frag / 40) & 7;
  int ug   = frag / 320;
  int quad = lane >> 4, n = lane & 15;
  int col  = (n >> 2) * 1024 + ug * 32 + ct * 4 + (n & 3);
  int k0   = kk * 32 + quad * 8;
  short8 v;
#pragma unroll
  for (int j = 0; j < 8; ++j) {
    int k = k0 + j;
    float f = (k < 1024) ? U[(size_t)k * 4096 + col] : W[(size_t)(k - 1024) * 4096 + col];
    v[j] = f2bf(f);
  }
  *reinterpret_cast<short8*>(upack + (size_t)idx * 8) = v;
}

__global__ void convert_x(const float* __restrict__ x, short* __restrict__ xbf) {
  int idx = blockIdx.x * 256 + threadIdx.x;
  const float* xp = x + (size_t)idx * 8;
  short8 v;
#pragma unroll
  for (int j = 0; j < 8; ++j) v[j] = f2bf(xp[j]);
  *reinterpret_cast<short8*>(xbf + (size_t)idx * 8) = v;
}

// zero hx + flags + zb at the device coherence point.
__global__ void init_state(unsigned int* __restrict__ base) {
  int idx = blockIdx.x * 256 + threadIdx.x;    // 258 blocks
  if (idx < 65808)
    __hip_atomic_store(&base[idx], 0u, __ATOMIC_RELAXED, __HIP_MEMORY_SCOPE_AGENT);
}

// ---- persistent stepper: 256 WGs x 256 threads ----
__global__ __launch_bounds__(256, 1) void lstm_persist(
    const short* __restrict__ xbf,      // [64][512][256] bf16
    const short* __restrict__ upack,    // per-ug packed B frags
    const float* __restrict__ bias,     // [4096] f32
    char* __restrict__ hx,              // [8 mach][2 par][8 rows][1024] bf16
    int* __restrict__ arrive,           // [8 mach][32 slots] contiguous
    const short* __restrict__ zb,       // 64B zeros (x pad-row A-frags)
    float* __restrict__ out)
{
  __shared__ short hlds[16384];         // 32KB: 16 padded rows x 1024 bf16 (swizzled)
  __shared__ float zlds[8][8][17];      // 4.4KB gate staging

  const int m    = blockIdx.x >> 5;     // logical machine: rows [8m, 8m+8)
  const int slot = blockIdx.x & 31;     // unit group within machine
  const int ub   = slot * 32;           // first unit owned by this WG

  const int tid  = threadIdx.x;
  const int wave = tid >> 6;
  const int lane = tid & 63;
  const int quad = lane >> 4;
  const int l15  = lane & 15;
  const int te   = 2 * wave, to = 2 * wave + 1;   // this wave's col-tiles

  // elementwise identity: thread -> (row, unit)
  const int erow = tid >> 5;            // 0..7 local row
  const int us   = tid & 31;
  const int ui   = us & 3, ct_e = us >> 2;
  const int unit = ub + us;
  const float bi = bias[unit],        bfv = bias[1024 + unit];
  const float bg = bias[2048 + unit], bo  = bias[3072 + unit];
  float cst = 0.f;

  // ---- U-weights fully VGPR-resident (256 VGPR) ----
  const short* wbase = upack + (size_t)slot * (8 * 40 * 64 * 8);
  short8 wUe[32], wUo[32];
#pragma unroll
  for (int ks = 0; ks < 32; ++ks) {
    wUe[ks] = *reinterpret_cast<const short8*>(wbase + (((size_t)te * 40 + ks) * 64 + lane) * 8);
    wUo[ks] = *reinterpret_cast<const short8*>(wbase + (((size_t)to * 40 + ks) * 64 + lane) * 8);
  }
  {  // zero hlds pad rows 8..15 (XOR bijective per row; zeros everywhere anyway)
    int r = 8 + (tid >> 5), seg = tid & 31;
    short8 z = {0, 0, 0, 0, 0, 0, 0, 0};
    const int sw = (r & 7) << 4;
#pragma unroll
    for (int j = 0; j < 4; ++j) {
      int b = seg * 16 + j * 512;
      *reinterpret_cast<short8*>((char*)hlds + r * 2048 + (b ^ sw)) = z;
    }
  }
  __syncthreads();

  // x@W partials for this wave's two tiles (B-frags from cached upack)
  floatx4 xe0, xe1, xo0, xo1;
  auto xw = [&](int t) {
    floatx4 z4 = {0.f, 0.f, 0.f, 0.f};
    floatx4 e0 = z4, e1 = z4, o0 = z4, o1 = z4;
    const short* xr = (l15 < 8)
        ? xbf + (((size_t)(8 * m + l15) * 512 + t) * 256 + quad * 8)
        : zb + quad * 8;                       // pad rows read zeros
    const int xstep = (l15 < 8) ? 32 : 0;
    const short* wbe = wbase + (((size_t)te * 40 + 32) * 64 + lane) * 8;
    const short* wbo = wbase + (((size_t)to * 40 + 32) * 64 + lane) * 8;
#pragma unroll
    for (int ks = 0; ks < 8; ++ks) {
      short8 A  = *reinterpret_cast<const short8*>(xr); xr += xstep;
      short8 Be = *reinterpret_cast<const short8*>(wbe + ks * 512);
      short8 Bo = *reinterpret_cast<const short8*>(wbo + ks * 512);
      if (ks & 1) { e1 = BMFMA(A, Be, e1, 0, 0, 0); o1 = BMFMA(A, Bo, o1, 0, 0, 0); }
      else        { e0 = BMFMA(A, Be, e0, 0, 0, 0); o0 = BMFMA(A, Bo, o0, 0, 0, 0); }
    }
    xe0 = e0; xe1 = e1; xo0 = o0; xo1 = o1;
  };
  xw(0);

  const int stage_r = tid >> 5, stage_seg = tid & 31;
  int* flagp = arrive + m * 32;

  for (int t = 0; t < 512; ++t) {
    // 1. wave0 polls this machine's 32 contiguous flags (2 lines); t=0 trivial
    if (t > 0 && wave == 0) {
      for (;;) {
        int v = (lane < 32)
                  ? __hip_atomic_load(flagp + lane, __ATOMIC_RELAXED,
                                      __HIP_MEMORY_SCOPE_AGENT)
                  : t;
        if (__all(v >= t)) break;
      }
    }
    __syncthreads();
    // 2. stage h(t) (16KB) from MALL into swizzled LDS (64B/thread)
    {
      const char* src = hx + ((size_t)(m * 2 + (t & 1)) << 14)
                      + stage_r * 2048 + stage_seg * 16;
      short8 v0, v1, v2, v3;
      asm volatile("global_load_dwordx4 %0, %4, off sc0 sc1\n\t"
                   "global_load_dwordx4 %1, %4, off offset:512 sc0 sc1\n\t"
                   "global_load_dwordx4 %2, %4, off offset:1024 sc0 sc1\n\t"
                   "global_load_dwordx4 %3, %4, off offset:1536 sc0 sc1\n\t"
                   "s_waitcnt vmcnt(0)"
                   : "=&v"(v0), "=&v"(v1), "=&v"(v2), "=&v"(v3)
                   : "v"(src) : "memory");
      char* dbase = (char*)hlds + stage_r * 2048;
      const int sw = (stage_r & 7) << 4;
      const int b0 = stage_seg * 16;
      *reinterpret_cast<short8*>(dbase + ((b0       ) ^ sw)) = v0;
      *reinterpret_cast<short8*>(dbase + ((b0 +  512) ^ sw)) = v1;
      *reinterpret_cast<short8*>(dbase + ((b0 + 1024) ^ sw)) = v2;
      *reinterpret_cast<short8*>(dbase + ((b0 + 1536) ^ sw)) = v3;
    }
    __syncthreads();
    // 3. h@U ladder: A from swizzled LDS, U-weights from VGPRs
    floatx4 aE0 = xe0, aE1 = xe1, aO0 = xo0, aO1 = xo1;
    {
      const char* hb = (const char*)hlds + l15 * 2048;
      const int rx = (l15 & 7) << 4;
#pragma unroll
      for (int ks = 0; ks < 32; ++ks) {
        short8 A = *reinterpret_cast<const short8*>(hb + ((ks * 64 + quad * 16) ^ rx));
        if (ks & 1) { aE1 = BMFMA(A, wUe[ks], aE1, 0, 0, 0); aO1 = BMFMA(A, wUo[ks], aO1, 0, 0, 0); }
        else        { aE0 = BMFMA(A, wUe[ks], aE0, 0, 0, 0); aO0 = BMFMA(A, wUo[ks], aO0, 0, 0, 0); }
      }
    }
    floatx4 aE = aE0 + aE1, aO = aO0 + aO1;
    // 4. transpose to zlds (C: col=l15, row=quad*4+i; only rows<8 real)
    if (quad < 2) {
#pragma unroll
      for (int i = 0; i < 4; ++i) {
        int row = quad * 4 + i;
        zlds[row][te][l15] = aE[i];
        zlds[row][to][l15] = aO[i];
      }
    }
    __syncthreads();
    // 5. elementwise (thread owns one (row, unit))
    float zi = zlds[erow][ct_e][0 + ui] + bi;
    float zf = zlds[erow][ct_e][4 + ui] + bfv;
    float zg = zlds[erow][ct_e][8 + ui] + bg;
    float zo = zlds[erow][ct_e][12 + ui] + bo;
    float ig = sigm(zi), fg = sigm(zf), gg = tanh_fast(zg), og = sigm(zo);
    cst = fg * cst + ig * gg;
    float hn = og * tanh_fast(cst);

    if (t < 511) {
      // 6. pack 4 units -> one 8B AGENT store into machine h buffer
      float hn1 = __shfl_xor(hn, 1);
      unsigned int p01 = (unsigned int)(unsigned short)f2bf(hn) |
                         ((unsigned int)(unsigned short)f2bf(hn1) << 16);
      unsigned int pot = __shfl_xor(p01, 2);
      if (ui == 0) {
        unsigned long long v = (unsigned long long)p01 |
                               ((unsigned long long)pot << 32);
        unsigned long long* dst = (unsigned long long*)
            (hx + ((size_t)(m * 2 + ((t + 1) & 1)) << 14)
                + erow * 2048 + (size_t)(ub + (us & ~3)) * 2);
        __hip_atomic_store(dst, v, __ATOMIC_RELAXED, __HIP_MEMORY_SCOPE_AGENT);
      }
      asm volatile("s_waitcnt vmcnt(0)" ::: "memory");  // h stores acked
      __syncthreads();                                  // all 4 waves drained
      if (tid == 0)
        __hip_atomic_store(flagp + slot, t + 1, __ATOMIC_RELAXED,
                           __HIP_MEMORY_SCOPE_AGENT);
      out[((size_t)(8 * m + erow) * 512 + t) * 1024 + unit] = hn;  // off critical path
      xw(t + 1);                                        // hides flag flight
    } else {
      size_t gr = 8 * m + erow;
      out[(gr * 512 + 511) * 1024 + unit] = hn;
      out[(size_t)SEQ_N + gr * 1024 + unit] = hn;              // h_last
      out[(size_t)SEQ_N + 65536 + gr * 1024 + unit] = cst;     // c_last
    }
  }
}

extern "C" void kernel_launch(void* const* d_in, const int* in_sizes, int n_in,
                              void* d_out, int out_size, void* d_ws, size_t ws_size,
                              hipStream_t stream) {
  const float* x    = (const float*)d_in[0];
  const float* W    = (const float*)d_in[1];
  const float* U    = (const float*)d_in[2];
  const float* bias = (const float*)d_in[3];
  float* out = (float*)d_out;
  char* ws = (char*)d_ws;

  short* upack = (short*)ws;                       // 10,485,760 B
  short* xbf   = (short*)(ws + 10485760);          // 16,777,216 B
  char*  hx    = ws + 27262976;                    //    262,144 B
  int*   arrive= (int*)(ws + 27525120);            //      1,024 B
  short* zb    = (short*)(ws + 27526144);          //         64 B
  (void)in_sizes; (void)n_in; (void)out_size; (void)ws_size;

  init_state<<<258, 256, 0, stream>>>((unsigned int*)(ws + 27262976));
  pack_weights<<<2560, 256, 0, stream>>>(W, U, upack);
  convert_x<<<4096, 256, 0, stream>>>(x, xbf);
  lstm_persist<<<256, 256, 0, stream>>>(xbf, upack, bias, hx, arrive, zb, out);
}